// Round 13
// baseline (86.249 us; speedup 1.0000x reference)
//
#include <hip/hip_runtime.h>

#define B_ 2
#define C_ 256
#define HW_ 64
#define N_ 4096
#define K_SEL 1228   // int(4096*0.3)
#define MIP_ 16
#define FIXSCALE 1099511627776.0           // 2^40
#define INVFIXSCALE 9.094947017729282e-13  // 2^-40

__device__ __forceinline__ float sigm(float z) { return 1.0f / (1.0f + expf(-z)); }

// ---------------------------------------------------------------- k_pre
// One block per (b,c): row/col means (LDS-local), then scatter the conv
// contribution w1[o,c]*Y[seg,c,pos] into racc[b][seg*64+pos][o] as int64
// fixed-point atomicAdds (deterministic: integer adds commute).
__global__ __launch_bounds__(256) void k_pre(
    const float* __restrict__ x, const float* __restrict__ w1,
    unsigned long long* __restrict__ racc) {
  __shared__ float rp[64][17];
  __shared__ float cp[16][65];
  __shared__ float Yl[128];
  int bc = blockIdx.x, t = threadIdx.x;
  int b = bc >> 8, c = bc & 255;
  const float* src = x + (size_t)bc * N_;
  int g = t >> 4, b16 = t & 15;
  float c0 = 0, c1 = 0, c2 = 0, c3 = 0;
  #pragma unroll
  for (int it = 0; it < 4; ++it) {
    int row = it * 16 + g;
    float4 v = *(const float4*)&src[row * 64 + b16 * 4];
    rp[row][b16] = v.x + v.y + v.z + v.w;
    c0 += v.x; c1 += v.y; c2 += v.z; c3 += v.w;
  }
  cp[g][b16 * 4 + 0] = c0;
  cp[g][b16 * 4 + 1] = c1;
  cp[g][b16 * 4 + 2] = c2;
  cp[g][b16 * 4 + 3] = c3;
  __syncthreads();
  if (t < 64) {
    float rs = 0;
    #pragma unroll
    for (int i = 0; i < 16; ++i) rs += rp[t][i];
    Yl[t] = rs * (1.0f / 64.0f);
    float cs = 0;
    #pragma unroll
    for (int gg = 0; gg < 16; ++gg) cs += cp[gg][t];
    Yl[64 + t] = cs * (1.0f / 64.0f);
  }
  __syncthreads();

  // scatter: thread -> (p = seg*64+pos, 8 output channels)
  int p = t & 127;
  int oq = __builtin_amdgcn_readfirstlane(t >> 7);   // wave-uniform 0/1
  float yv = Yl[p];
  const float* wq = w1 + (oq * 8) * C_ + c;          // + oo*C_ : s_loads
  unsigned long long* dst = racc + ((size_t)(b * 128 + p)) * 16 + oq * 8;
  #pragma unroll
  for (int oo = 0; oo < 8; ++oo) {
    float contrib = wq[oo * C_] * yv;
    long long q = (long long)((double)contrib * FIXSCALE);
    atomicAdd(&dst[oo], (unsigned long long)q);
  }
}

// ---------------------------------------------------------------- k_fin
// One block per (b,c). Reads racc (16KB/batch), converts to float, BN+ReLU+
// attention dots + sigmoids locally (t<128, one (seg,pos) each), then the
// validated selection + moments + output.
__global__ __launch_bounds__(256) void k_fin(
    const float* __restrict__ x,
    const unsigned long long* __restrict__ racc,
    const float* __restrict__ b1,
    const float* __restrict__ gam, const float* __restrict__ bet,
    const float* __restrict__ mea, const float* __restrict__ var,
    const float* __restrict__ wh, const float* __restrict__ bh,
    const float* __restrict__ ww, const float* __restrict__ bw,
    const float* __restrict__ wd1, const float* __restrict__ bd1,
    const float* __restrict__ wd2, const float* __restrict__ bd2,
    const float* __restrict__ msk,
    float* __restrict__ out) {
  __shared__ float ahs[HW_], sds[HW_], sws[HW_], sps[HW_];
  __shared__ int icomb[4];
  __shared__ float fmn[4], fmx[4];
  __shared__ float red[15][4];
  __shared__ float ps[15];

  int bc = blockIdx.x, t = threadIdx.x;
  int b = bc >> 8;

  // prefetch this block's image (16 floats/thread)
  const float* xr = x + (size_t)bc * N_;
  float4 xv[4];
  #pragma unroll
  for (int it = 0; it < 4; ++it)
    xv[it] = *(const float4*)&xr[it * 1024 + t * 4];

  // ===== conv epilogue from racc (t<128: one (seg,pos) each)
  if (t < 128) {
    int seg = t >> 6, pos = t & 63;
    const unsigned long long* rsrc = racc + ((size_t)(b * 128 + t)) * 16;
    float aH = bh[0], aW = bw[0], aD1 = bd1[0], aD2 = bd2[0];
    #pragma unroll
    for (int o = 0; o < MIP_; ++o) {
      long long q = (long long)rsrc[o];
      float r = (float)((double)q * INVFIXSCALE);
      float sc = gam[o] * rsqrtf(var[o] + 1e-5f);
      float y = r + b1[o] - mea[o];
      float rr = fmaxf(fmaf(y, sc, bet[o]), 0.0f);
      aH = fmaf(wh[o], rr, aH);
      aW = fmaf(ww[o], rr, aW);
      aD1 = fmaf(wd1[o], rr, aD1);
      aD2 = fmaf(wd2[o], rr, aD2);
    }
    if (seg == 0) {
      ahs[pos] = sigm(aH);
      sds[pos] = sigm(aD1) * sigm(aD2);
    } else {
      sws[pos] = sigm(aW);
    }
  }
  __syncthreads();
  if (t < 64) sps[t] = sws[t] * sds[t];
  __syncthreads();

  // ===== Stage C: selection + moments + output (validated)
  float4 sp4 = *(const float4*)&sps[(t * 4) & 63];
  const float spe[4] = {sp4.x, sp4.y, sp4.z, sp4.w};
  float ahv[4];
  #pragma unroll
  for (int it = 0; it < 4; ++it) ahv[it] = ahs[it * 16 + (t >> 4)];

  float v[16];
  #pragma unroll
  for (int it = 0; it < 4; ++it)
    #pragma unroll
    for (int e = 0; e < 4; ++e) v[it * 4 + e] = ahv[it] * spe[e];

  float mn = v[0], mx = v[0];
  #pragma unroll
  for (int k = 1; k < 16; ++k) { mn = fminf(mn, v[k]); mx = fmaxf(mx, v[k]); }
  #pragma unroll
  for (int o = 32; o; o >>= 1) {
    mn = fminf(mn, __shfl_xor(mn, o, 64));
    mx = fmaxf(mx, __shfl_xor(mx, o, 64));
  }
  if ((t & 63) == 0) { fmn[t >> 6] = mn; fmx[t >> 6] = mx; }
  __syncthreads();
  mn = fminf(fminf(fmn[0], fmn[1]), fminf(fmn[2], fmn[3]));
  mx = fmaxf(fmaxf(fmx[0], fmx[1]), fmaxf(fmx[2], fmx[3]));

  unsigned lo = __float_as_uint(mn);        // cnt_ge(lo) = 4096 >= K
  unsigned hi = __float_as_uint(mx) + 1u;   // cnt_ge(hi) = 0 < K
  while (hi - lo > 8192u) {
    unsigned mid = lo + ((hi - lo) >> 1);
    float midf = __uint_as_float(mid);
    int cnt = 0;
    #pragma unroll
    for (int k = 0; k < 16; ++k) cnt += (v[k] >= midf) ? 1 : 0;
    #pragma unroll
    for (int o = 32; o; o >>= 1) cnt += __shfl_xor(cnt, o, 64);
    if ((t & 63) == 0) icomb[t >> 6] = cnt;
    __syncthreads();
    int total = icomb[0] + icomb[1] + icomb[2] + icomb[3];
    __syncthreads();
    if (total >= K_SEL) lo = mid; else hi = mid;
  }
  float thr = __uint_as_float(lo);
  float gm = sigm(msk[0]);

  // acc[0..6] = q1..q7, acc[7] = T, acc[8..14] = P1..P7
  float acc[15];
  #pragma unroll
  for (int m = 0; m < 15; ++m) acc[m] = 0.0f;
  #pragma unroll
  for (int it = 0; it < 4; ++it) {
    const float xe[4] = {xv[it].x, xv[it].y, xv[it].z, xv[it].w};
    #pragma unroll
    for (int e = 0; e < 4; ++e) {
      float vv = v[it * 4 + e];
      float xx = xe[e];
      acc[7] += xx;
      if (vv >= thr) {
        float p = vv;
        acc[0] += p;
        acc[8] = fmaf(p, xx, acc[8]); p *= vv;
        acc[1] += p;
        acc[9] = fmaf(p, xx, acc[9]); p *= vv;
        acc[2] += p;
        acc[10] = fmaf(p, xx, acc[10]); p *= vv;
        acc[3] += p;
        acc[11] = fmaf(p, xx, acc[11]); p *= vv;
        acc[4] += p;
        acc[12] = fmaf(p, xx, acc[12]); p *= vv;
        acc[5] += p;
        acc[13] = fmaf(p, xx, acc[13]); p *= vv;
        acc[6] += p;
        acc[14] = fmaf(p, xx, acc[14]);
      }
    }
  }
  #pragma unroll
  for (int m = 0; m < 15; ++m) {
    float s = acc[m];
    #pragma unroll
    for (int o = 32; o; o >>= 1) s += __shfl_xor(s, o, 64);
    if ((t & 63) == 0) red[m][t >> 6] = s;
  }
  __syncthreads();
  if (t < 15) {
    const float invf[15] = {1.0f, 0.5f, 1.0f / 6.0f, 1.0f / 24.0f,
                            1.0f / 120.0f, 1.0f / 720.0f, 1.0f / 5040.0f,
                            1.0f,
                            1.0f, 0.5f, 1.0f / 6.0f, 1.0f / 24.0f,
                            1.0f / 120.0f, 1.0f / 720.0f, 1.0f / 5040.0f};
    ps[t] = (red[t][0] + red[t][1] + red[t][2] + red[t][3]) * invf[t];
  }
  __syncthreads();
  float q1 = ps[0], q2 = ps[1], q3 = ps[2], q4 = ps[3];
  float q5 = ps[4], q6 = ps[5], q7 = ps[6];
  float T = ps[7];
  float p1 = ps[8], p2 = ps[9], p3 = ps[10], p4 = ps[11];
  float p5 = ps[12], p6 = ps[13], p7 = ps[14];

  float* ob = out + (size_t)bc * N_;
  #pragma unroll
  for (int it = 0; it < 4; ++it) {
    float o4[4];
    #pragma unroll
    for (int e = 0; e < 4; ++e) {
      float alpha = gm * v[it * 4 + e];
      float hn = p7;
      hn = fmaf(alpha, hn, p6);
      hn = fmaf(alpha, hn, p5);
      hn = fmaf(alpha, hn, p4);
      hn = fmaf(alpha, hn, p3);
      hn = fmaf(alpha, hn, p2);
      hn = fmaf(alpha, hn, p1);
      float numer = fmaf(alpha, hn, T);
      float hd = q7;
      hd = fmaf(alpha, hd, q6);
      hd = fmaf(alpha, hd, q5);
      hd = fmaf(alpha, hd, q4);
      hd = fmaf(alpha, hd, q3);
      hd = fmaf(alpha, hd, q2);
      hd = fmaf(alpha, hd, q1);
      float denom = fmaf(alpha, hd, (float)N_);
      o4[e] = numer / denom;
    }
    *(float4*)&ob[it * 1024 + t * 4] = make_float4(o4[0], o4[1], o4[2], o4[3]);
  }
}

extern "C" void kernel_launch(void* const* d_in, const int* in_sizes, int n_in,
                              void* d_out, int out_size, void* d_ws, size_t ws_size,
                              hipStream_t stream) {
  (void)in_sizes; (void)n_in; (void)out_size; (void)ws_size;
  const float* x   = (const float*)d_in[0];
  const float* w1  = (const float*)d_in[1];
  const float* b1  = (const float*)d_in[2];
  const float* gam = (const float*)d_in[3];
  const float* bet = (const float*)d_in[4];
  const float* mea = (const float*)d_in[5];
  const float* var = (const float*)d_in[6];
  const float* wh  = (const float*)d_in[7];
  const float* bh  = (const float*)d_in[8];
  const float* ww  = (const float*)d_in[9];
  const float* bw  = (const float*)d_in[10];
  const float* wd1 = (const float*)d_in[11];
  const float* bd1 = (const float*)d_in[12];
  const float* wd2 = (const float*)d_in[13];
  const float* bd2 = (const float*)d_in[14];
  const float* msk = (const float*)d_in[15];
  float* out = (float*)d_out;

  unsigned long long* racc = (unsigned long long*)d_ws;   // 4096 int64 = 32KB

  hipMemsetAsync(racc, 0, (size_t)B_ * 128 * 16 * sizeof(unsigned long long),
                 stream);
  hipLaunchKernelGGL(k_pre, dim3(B_ * C_), dim3(256), 0, stream, x, w1, racc);
  hipLaunchKernelGGL(k_fin, dim3(B_ * C_), dim3(256), 0, stream,
                     x, racc, b1, gam, bet, mea, var,
                     wh, bh, ww, bw, wd1, bd1, wd2, bd2, msk, out);
}

// Round 14
// 24.702 us; speedup vs baseline: 3.4915x; 3.4915x over previous
//
#include <hip/hip_runtime.h>

#define B_ 2
#define C_ 256
#define HW_ 64
#define N_ 4096
#define K_SEL 1228   // int(4096*0.3)
#define MIP_ 16

__device__ __forceinline__ float sigm(float z) { return 1.0f / (1.0f + expf(-z)); }

// ---------------------------------------------------------------- k_pre
// One block per (b,c): row means and col means, stored TRANSPOSED:
// xhT[((b*2+seg)*64 + pos)*256 + c],  seg 0 = row-mean (x_h), 1 = col-mean (x_w)
__global__ __launch_bounds__(256) void k_pre(const float* __restrict__ x,
                                             float* __restrict__ xhT) {
  __shared__ float rp[64][17];
  __shared__ float cp[16][65];
  int bc = blockIdx.x, t = threadIdx.x;
  int b = bc >> 8, c = bc & 255;
  const float* src = x + (size_t)bc * N_;
  int g = t >> 4, b16 = t & 15;
  float c0 = 0, c1 = 0, c2 = 0, c3 = 0;
  #pragma unroll
  for (int it = 0; it < 4; ++it) {
    int row = it * 16 + g;
    float4 v = *(const float4*)&src[row * 64 + b16 * 4];
    rp[row][b16] = v.x + v.y + v.z + v.w;
    c0 += v.x; c1 += v.y; c2 += v.z; c3 += v.w;
  }
  cp[g][b16 * 4 + 0] = c0;
  cp[g][b16 * 4 + 1] = c1;
  cp[g][b16 * 4 + 2] = c2;
  cp[g][b16 * 4 + 3] = c3;
  __syncthreads();
  if (t < 64) {
    float rs = 0;
    #pragma unroll
    for (int i = 0; i < 16; ++i) rs += rp[t][i];
    xhT[(((b * 2 + 0) * 64 + t) << 8) + c] = rs * (1.0f / 64.0f);
    float cs = 0;
    #pragma unroll
    for (int gg = 0; gg < 16; ++gg) cs += cp[gg][t];
    xhT[(((b * 2 + 1) * 64 + t) << 8) + c] = cs * (1.0f / 64.0f);
  }
}

// ---------------------------------------------------------------- k_conv
// One block (1 wave) per (b,seg,pos) row: 16-output 256-long conv via wave
// reduction, BN+ReLU, attention dots + sigmoids. Writes ah / sw / sd.
__global__ __launch_bounds__(64) void k_conv(
    const float* __restrict__ xhT,
    const float* __restrict__ w1, const float* __restrict__ b1,
    const float* __restrict__ gam, const float* __restrict__ bet,
    const float* __restrict__ mea, const float* __restrict__ var,
    const float* __restrict__ wh, const float* __restrict__ bh,
    const float* __restrict__ ww, const float* __restrict__ bw,
    const float* __restrict__ wd1, const float* __restrict__ bd1,
    const float* __restrict__ wd2, const float* __restrict__ bd2,
    float* __restrict__ ahb, float* __restrict__ swb, float* __restrict__ sdb) {
  int blk = blockIdx.x;            // (b*2+seg)*64 + pos
  int l = threadIdx.x;             // 0..63
  const float* yrow = xhT + ((size_t)blk << 8);
  float4 v = *(const float4*)&yrow[l * 4];
  float r[MIP_];
  #pragma unroll
  for (int o = 0; o < MIP_; ++o) {
    float4 wv = *(const float4*)&w1[o * C_ + l * 4];
    float p = fmaf(v.x, wv.x, fmaf(v.y, wv.y, fmaf(v.z, wv.z, v.w * wv.w)));
    #pragma unroll
    for (int off = 32; off; off >>= 1) p += __shfl_xor(p, off, 64);
    r[o] = p;   // full sum, present in all lanes
  }
  float aH = bh[0], aW = bw[0], aD1 = bd1[0], aD2 = bd2[0];
  #pragma unroll
  for (int o = 0; o < MIP_; ++o) {
    float sc = gam[o] * rsqrtf(var[o] + 1e-5f);
    float y = r[o] + b1[o] - mea[o];
    float rr = fmaxf(fmaf(y, sc, bet[o]), 0.0f);
    aH = fmaf(wh[o], rr, aH);
    aW = fmaf(ww[o], rr, aW);
    aD1 = fmaf(wd1[o], rr, aD1);
    aD2 = fmaf(wd2[o], rr, aD2);
  }
  if (l == 0) {
    int seg = (blk >> 6) & 1, b = blk >> 7, pos = blk & 63;
    if (seg == 0) {
      ahb[b * HW_ + pos] = sigm(aH);
      sdb[b * HW_ + pos] = sigm(aD1) * sigm(aD2);
    } else {
      swb[b * HW_ + pos] = sigm(aW);
    }
  }
}

// ---------------------------------------------------------------- k_fin
// One block per (b,c). Redundant (parallel) selection: products 16/thread in
// regs, bit-bisection (32768-ULP stop, 1 barrier/iter), q+P moments over
// register-prefetched x, output.
__global__ __launch_bounds__(256) void k_fin(
    const float* __restrict__ x,
    const float* __restrict__ ahb, const float* __restrict__ swb,
    const float* __restrict__ sdb, const float* __restrict__ msk,
    float* __restrict__ out) {
  __shared__ float ahs[HW_], sps[HW_];
  __shared__ int icomb[2][4];
  __shared__ float fmn[4], fmx[4];
  __shared__ float red[15][4];
  __shared__ float ps[15];
  int bc = blockIdx.x, b = bc >> 8, t = threadIdx.x;
  const float* xr = x + (size_t)bc * N_;

  // start the mask sigmoid early (overlaps with everything below)
  float gm = sigm(msk[0]);

  // prefetch x (16 values) — latency hides under selection phase
  float4 xv[4];
  #pragma unroll
  for (int it = 0; it < 4; ++it)
    xv[it] = *(const float4*)&xr[it * 1024 + t * 4];

  if (t < HW_) {
    ahs[t] = ahb[b * HW_ + t];
    sps[t] = swb[b * HW_ + t] * sdb[b * HW_ + t];
  }
  __syncthreads();

  // unified index map: j = it*1024 + 4t + e  ->  h = it*16 + (t>>4), w = (4t+e)&63
  float4 sp4 = *(const float4*)&sps[(t * 4) & 63];
  const float spe[4] = {sp4.x, sp4.y, sp4.z, sp4.w};
  float ahv[4];
  #pragma unroll
  for (int it = 0; it < 4; ++it) ahv[it] = ahs[it * 16 + (t >> 4)];

  float v[16];
  #pragma unroll
  for (int it = 0; it < 4; ++it)
    #pragma unroll
    for (int e = 0; e < 4; ++e) v[it * 4 + e] = ahv[it] * spe[e];

  // global min / max (positive floats: float order == bit order)
  float mn = v[0], mx = v[0];
  #pragma unroll
  for (int k = 1; k < 16; ++k) { mn = fminf(mn, v[k]); mx = fmaxf(mx, v[k]); }
  #pragma unroll
  for (int o = 32; o; o >>= 1) {
    mn = fminf(mn, __shfl_xor(mn, o, 64));
    mx = fmaxf(mx, __shfl_xor(mx, o, 64));
  }
  if ((t & 63) == 0) { fmn[t >> 6] = mn; fmx[t >> 6] = mx; }
  __syncthreads();
  mn = fminf(fminf(fmn[0], fmn[1]), fminf(fmn[2], fmn[3]));
  mx = fmaxf(fmaxf(fmx[0], fmx[1]), fmaxf(fmx[2], fmx[3]));

  unsigned lo = __float_as_uint(mn);        // cnt_ge(lo) = 4096 >= K
  unsigned hi = __float_as_uint(mx) + 1u;   // cnt_ge(hi) = 0 < K
  int par = 0;
  while (hi - lo > 32768u) {
    unsigned mid = lo + ((hi - lo) >> 1);
    float midf = __uint_as_float(mid);
    int cnt = 0;
    #pragma unroll
    for (int k = 0; k < 16; ++k) cnt += (v[k] >= midf) ? 1 : 0;
    #pragma unroll
    for (int o = 32; o; o >>= 1) cnt += __shfl_xor(cnt, o, 64);
    if ((t & 63) == 0) icomb[par][t >> 6] = cnt;
    __syncthreads();   // one barrier per iter: reads of [par] precede writes of [par^1]
    int total = icomb[par][0] + icomb[par][1] + icomb[par][2] + icomb[par][3];
    if (total >= K_SEL) lo = mid; else hi = mid;
    par ^= 1;
  }
  float thr = __uint_as_float(lo);

  // acc[0..6] = q1..q7 (from f over S), acc[7] = T, acc[8..14] = P1..P7
  float acc[15];
  #pragma unroll
  for (int m = 0; m < 15; ++m) acc[m] = 0.0f;
  #pragma unroll
  for (int it = 0; it < 4; ++it) {
    const float xe[4] = {xv[it].x, xv[it].y, xv[it].z, xv[it].w};
    #pragma unroll
    for (int e = 0; e < 4; ++e) {
      float vv = v[it * 4 + e];
      float xx = xe[e];
      acc[7] += xx;
      if (vv >= thr) {
        float p = vv;
        acc[0] += p;
        acc[8] = fmaf(p, xx, acc[8]); p *= vv;
        acc[1] += p;
        acc[9] = fmaf(p, xx, acc[9]); p *= vv;
        acc[2] += p;
        acc[10] = fmaf(p, xx, acc[10]); p *= vv;
        acc[3] += p;
        acc[11] = fmaf(p, xx, acc[11]); p *= vv;
        acc[4] += p;
        acc[12] = fmaf(p, xx, acc[12]); p *= vv;
        acc[5] += p;
        acc[13] = fmaf(p, xx, acc[13]); p *= vv;
        acc[6] += p;
        acc[14] = fmaf(p, xx, acc[14]);
      }
    }
  }
  __syncthreads();   // icomb/fmn reuse-safety before red[] phase barrier pattern
  #pragma unroll
  for (int m = 0; m < 15; ++m) {
    float s = acc[m];
    #pragma unroll
    for (int o = 32; o; o >>= 1) s += __shfl_xor(s, o, 64);
    if ((t & 63) == 0) red[m][t >> 6] = s;
  }
  __syncthreads();
  if (t < 15) {
    // scale: q_m and P_m by 1/m! (T unscaled)
    const float invf[15] = {1.0f, 0.5f, 1.0f / 6.0f, 1.0f / 24.0f,
                            1.0f / 120.0f, 1.0f / 720.0f, 1.0f / 5040.0f,
                            1.0f,
                            1.0f, 0.5f, 1.0f / 6.0f, 1.0f / 24.0f,
                            1.0f / 120.0f, 1.0f / 720.0f, 1.0f / 5040.0f};
    ps[t] = (red[t][0] + red[t][1] + red[t][2] + red[t][3]) * invf[t];
  }
  __syncthreads();
  float q1 = ps[0], q2 = ps[1], q3 = ps[2], q4 = ps[3];
  float q5 = ps[4], q6 = ps[5], q7 = ps[6];
  float T = ps[7];
  float p1 = ps[8], p2 = ps[9], p3 = ps[10], p4 = ps[11];
  float p5 = ps[12], p6 = ps[13], p7 = ps[14];

  float* ob = out + (size_t)bc * N_;
  #pragma unroll
  for (int it = 0; it < 4; ++it) {
    float o4[4];
    #pragma unroll
    for (int e = 0; e < 4; ++e) {
      float alpha = gm * v[it * 4 + e];
      float hn = p7;
      hn = fmaf(alpha, hn, p6);
      hn = fmaf(alpha, hn, p5);
      hn = fmaf(alpha, hn, p4);
      hn = fmaf(alpha, hn, p3);
      hn = fmaf(alpha, hn, p2);
      hn = fmaf(alpha, hn, p1);
      float numer = fmaf(alpha, hn, T);
      float hd = q7;
      hd = fmaf(alpha, hd, q6);
      hd = fmaf(alpha, hd, q5);
      hd = fmaf(alpha, hd, q4);
      hd = fmaf(alpha, hd, q3);
      hd = fmaf(alpha, hd, q2);
      hd = fmaf(alpha, hd, q1);
      float denom = fmaf(alpha, hd, (float)N_);
      o4[e] = numer / denom;
    }
    *(float4*)&ob[it * 1024 + t * 4] = make_float4(o4[0], o4[1], o4[2], o4[3]);
  }
}

extern "C" void kernel_launch(void* const* d_in, const int* in_sizes, int n_in,
                              void* d_out, int out_size, void* d_ws, size_t ws_size,
                              hipStream_t stream) {
  (void)in_sizes; (void)n_in; (void)out_size; (void)ws_size;
  const float* x   = (const float*)d_in[0];
  const float* w1  = (const float*)d_in[1];
  const float* b1  = (const float*)d_in[2];
  const float* gam = (const float*)d_in[3];
  const float* bet = (const float*)d_in[4];
  const float* mea = (const float*)d_in[5];
  const float* var = (const float*)d_in[6];
  const float* wh  = (const float*)d_in[7];
  const float* bh  = (const float*)d_in[8];
  const float* ww  = (const float*)d_in[9];
  const float* bw  = (const float*)d_in[10];
  const float* wd1 = (const float*)d_in[11];
  const float* bd1 = (const float*)d_in[12];
  const float* wd2 = (const float*)d_in[13];
  const float* bd2 = (const float*)d_in[14];
  const float* msk = (const float*)d_in[15];
  float* out = (float*)d_out;

  float* ws  = (float*)d_ws;
  float* xhT = ws;                        // 65536 floats
  float* ahb = ws + 65536;                // 128
  float* swb = ahb + 128;                 // 128
  float* sdb = swb + 128;                 // 128

  hipLaunchKernelGGL(k_pre, dim3(B_ * C_), dim3(256), 0, stream, x, xhT);
  hipLaunchKernelGGL(k_conv, dim3(B_ * 2 * HW_), dim3(64), 0, stream,
                     xhT, w1, b1, gam, bet, mea, var,
                     wh, bh, ww, bw, wd1, bd1, wd2, bd2, ahb, swb, sdb);
  hipLaunchKernelGGL(k_fin, dim3(B_ * C_), dim3(256), 0, stream,
                     x, ahb, swb, sdb, msk, out);
}